// Round 1
// 572.064 us; speedup vs baseline: 1.0549x; 1.0549x over previous
//
#include <hip/hip_runtime.h>
#include <hip/hip_bf16.h>

// DecoderBlock: h_t = tanh(x_t @ U + h_{t-1} @ V + b)
// BZ=256, SEQ=512, IN=HID=256. fp32 in/out.
//
// prep_B : U (fp32) -> bf16 B-fragment-ordered buffer (128 KB).
// xu_gemm: XU = x @ U + b via bf16 MFMA 16x16x32 (unchanged from prev round).
// rnn_rec: REWRITTEN. 1 WG per batch row, 512 thr (8 waves).
//          h_{t-1}@V via fp16 MFMA 16x16x32: h broadcast into all 16 A-rows
//          (identical A rows -> identical C rows -> every lane holds a valid
//          column sum, no cross-wave reduce). V held in-register as fp16
//          B-fragments (64 VGPR/lane). Ping-pong fp16 hbuf in LDS -> ONE
//          barrier per step. XU prefetched 2 steps ahead.

#define SEQn 512
#define HIDn 256

typedef __attribute__((ext_vector_type(4))) float    floatx4;
typedef __attribute__((ext_vector_type(8))) short    short8;
typedef __attribute__((ext_vector_type(8))) _Float16 half8;

__device__ __forceinline__ short f2bf(float f) {
    __hip_bfloat16 h = __float2bfloat16(f);
    return *reinterpret_cast<short*>(&h);
}

// ---------------------------------------------------------------------------
// Pack U[k][n] -> wsB chunks: chunk idx = (kb*4 + q)*256 + n holds
// U[kb*32 + q*8 + j][n] (j=0..7) as bf16. 8192 chunks x 16 B = 128 KB.
// ---------------------------------------------------------------------------
__global__ void prep_B(const float* __restrict__ U, short* __restrict__ wsB) {
    int idx = blockIdx.x * 256 + threadIdx.x;   // 0..8191
    int n  = idx & 255;
    int q  = (idx >> 8) & 3;
    int kb = idx >> 10;
    int k0 = kb * 32 + q * 8;
    short8 c;
    #pragma unroll
    for (int j = 0; j < 8; j++)
        c[j] = f2bf(U[(size_t)(k0 + j) * 256 + n]);
    *(short8*)(wsB + (size_t)idx * 8) = c;
}

// ---------------------------------------------------------------------------
// MFMA GEMM: block tile 128 rows x 128 cols, 4 waves. (unchanged)
// ---------------------------------------------------------------------------
__global__ __launch_bounds__(256, 4)
void xu_gemm(const float* __restrict__ X, const short* __restrict__ wsB,
             const float* __restrict__ bias, float* __restrict__ out)
{
    const int tid = threadIdx.x;
    const int l   = tid & 63;
    const int w   = tid >> 6;          // wave 0..3
    const int lr  = l & 15;
    const int q   = l >> 4;
    const int m0  = blockIdx.y * 128;
    const int n0  = blockIdx.x * 128;

    floatx4 acc[2][8];
    #pragma unroll
    for (int mt = 0; mt < 2; mt++)
        #pragma unroll
        for (int nt = 0; nt < 8; nt++)
            acc[mt][nt] = (floatx4){0.f, 0.f, 0.f, 0.f};

    const size_t rowA = (size_t)(m0 + 32 * w + lr);

    for (int kb = 0; kb < 8; kb++) {
        short8 af[2];
        #pragma unroll
        for (int mt = 0; mt < 2; mt++) {
            const float* p = X + (rowA + 16 * mt) * 256 + kb * 32 + q * 8;
            float4 a0 = *(const float4*)p;
            float4 a1 = *(const float4*)(p + 4);
            af[mt][0] = f2bf(a0.x); af[mt][1] = f2bf(a0.y);
            af[mt][2] = f2bf(a0.z); af[mt][3] = f2bf(a0.w);
            af[mt][4] = f2bf(a1.x); af[mt][5] = f2bf(a1.y);
            af[mt][6] = f2bf(a1.z); af[mt][7] = f2bf(a1.w);
        }
        #pragma unroll
        for (int nt = 0; nt < 8; nt++) {
            short8 bfr = *(const short8*)(wsB +
                ((size_t)(kb * 4 + q) * 256 + n0 + 16 * nt + lr) * 8);
            acc[0][nt] = __builtin_amdgcn_mfma_f32_16x16x32_bf16(af[0], bfr, acc[0][nt], 0, 0, 0);
            acc[1][nt] = __builtin_amdgcn_mfma_f32_16x16x32_bf16(af[1], bfr, acc[1][nt], 0, 0, 0);
        }
    }

    #pragma unroll
    for (int nt = 0; nt < 8; nt++) {
        float bv = bias[n0 + 16 * nt + lr];
        #pragma unroll
        for (int mt = 0; mt < 2; mt++) {
            #pragma unroll
            for (int r = 0; r < 4; r++) {
                int row = m0 + 32 * w + 16 * mt + 4 * q + r;
                out[(size_t)row * 256 + n0 + 16 * nt + lr] = acc[mt][nt][r] + bv;
            }
        }
    }
}

// ---------------------------------------------------------------------------
// Recurrence via MFMA. 1 WG per batch row, 512 threads (8 waves).
// Wave w owns output cols [32w, 32w+32) as 2 n-tiles of 16.
// A-frag: h broadcast to all 16 m-rows (ds_read_b128, addr depends on quad
// only). B-frag: vf[nt][c][j] = fp16 V[32c+8q+j][32w+16nt+lr], preloaded.
// C rows all identical -> acc[0] is the column sum in every lane.
// ---------------------------------------------------------------------------
__global__ __launch_bounds__(512, 2)
void rnn_rec(const float* __restrict__ enc, const float* __restrict__ V,
             float* __restrict__ out)
{
    __shared__ _Float16 hbuf[2][HIDn];   // ping-pong, 1 KB

    const int tid = threadIdx.x;
    const int w   = tid >> 6;        // wave 0..7
    const int l   = tid & 63;
    const int lr  = l & 15;
    const int q   = l >> 4;
    const int b   = blockIdx.x;
    const int c0  = 32 * w + lr;     // first owned column (nt=0)

    // ---- preload V as fp16 B-fragments: 16 frags x 8 halves = 64 VGPR ----
    half8 vf[2][8];
    #pragma unroll
    for (int c = 0; c < 8; c++) {
        const float* vp = V + (size_t)(32 * c + 8 * q) * HIDn + 32 * w + lr;
        #pragma unroll
        for (int nt = 0; nt < 2; nt++) {
            half8 tmp;
            #pragma unroll
            for (int j = 0; j < 8; j++)
                tmp[j] = (_Float16)vp[(size_t)j * HIDn + 16 * nt];
            vf[nt][c] = tmp;
        }
    }

    float* outEnc = out + (size_t)b * HIDn;
    float* outDec = out + (size_t)65536 + (size_t)b * SEQn * HIDn;

    // ---- h0 init + encoder passthrough ----
    if (tid < HIDn) {
        float h0 = enc[(size_t)b * HIDn + tid];
        outEnc[tid]  = h0;
        hbuf[0][tid] = (_Float16)h0;
    }

    // ---- XU prefetch pipeline, depth 2 (rows t and t+1 preloaded) ----
    float xu_cur0 = outDec[c0];
    float xu_cur1 = outDec[c0 + 16];
    float xu_nx0  = outDec[HIDn + c0];
    float xu_nx1  = outDec[HIDn + c0 + 16];

    __syncthreads();

    int p = 0;
    for (int t = 0; t < SEQn; t++) {
        // prefetch XU for t+2 (hides LLC/HBM latency across a full step)
        float pf0 = 0.f, pf1 = 0.f;
        if (t + 2 < SEQn) {
            const float* xp = outDec + (size_t)(t + 2) * HIDn;
            pf0 = xp[c0];
            pf1 = xp[c0 + 16];
        }

        // A-fragments: 8 k-chunks, 16 B each, address depends on quad only
        // (broadcast read -> identical A rows)
        half8 af[8];
        #pragma unroll
        for (int c = 0; c < 8; c++)
            af[c] = *(const half8*)&hbuf[p][32 * c + 8 * q];

        // 16 MFMAs as 4 independent 4-deep chains
        floatx4 a0a = (floatx4){0.f,0.f,0.f,0.f};
        floatx4 a0b = (floatx4){0.f,0.f,0.f,0.f};
        floatx4 a1a = (floatx4){0.f,0.f,0.f,0.f};
        floatx4 a1b = (floatx4){0.f,0.f,0.f,0.f};
        #pragma unroll
        for (int c = 0; c < 8; c += 2) {
            a0a = __builtin_amdgcn_mfma_f32_16x16x32_f16(af[c],     vf[0][c],     a0a, 0, 0, 0);
            a1a = __builtin_amdgcn_mfma_f32_16x16x32_f16(af[c],     vf[1][c],     a1a, 0, 0, 0);
            a0b = __builtin_amdgcn_mfma_f32_16x16x32_f16(af[c + 1], vf[0][c + 1], a0b, 0, 0, 0);
            a1b = __builtin_amdgcn_mfma_f32_16x16x32_f16(af[c + 1], vf[1][c + 1], a1b, 0, 0, 0);
        }

        float s0 = (a0a[0] + a0b[0]) + xu_cur0;
        float s1 = (a1a[0] + a1b[0]) + xu_cur1;
        float e0 = __expf(2.f * s0);
        float e1 = __expf(2.f * s1);
        float hv0 = 1.f - 2.f / (e0 + 1.f);
        float hv1 = 1.f - 2.f / (e1 + 1.f);

        if (q == 0) {   // quads 1-3 hold duplicates; one writer per column
            float* op = outDec + (size_t)t * HIDn;
            op[c0]      = hv0;
            op[c0 + 16] = hv1;
            hbuf[p ^ 1][c0]      = (_Float16)hv0;
            hbuf[p ^ 1][c0 + 16] = (_Float16)hv1;
        }

        xu_cur0 = xu_nx0; xu_cur1 = xu_nx1;
        xu_nx0  = pf0;    xu_nx1  = pf1;
        p ^= 1;
        __syncthreads();   // single barrier per step (ping-pong hbuf)
    }
}

extern "C" void kernel_launch(void* const* d_in, const int* in_sizes, int n_in,
                              void* d_out, int out_size, void* d_ws, size_t ws_size,
                              hipStream_t stream) {
    const float* enc  = (const float*)d_in[0];   // [256,256]
    const float* x    = (const float*)d_in[1];   // [256,512,256]
    const float* U    = (const float*)d_in[2];   // [256,256]
    const float* V    = (const float*)d_in[3];   // [256,256]
    const float* bias = (const float*)d_in[4];   // [256]
    float* out = (float*)d_out;                  // 65536 + 33554432 floats

    float* outDec = out + 65536;

    // bf16 B-frag scratch (128 KB): d_ws, or the 256 KB encoder-output region
    // of d_out as fallback (rnn_rec overwrites it only after xu_gemm is done).
    short* wsB = (ws_size >= 131072) ? (short*)d_ws : (short*)out;

    prep_B<<<32, 256, 0, stream>>>(U, wsB);

    dim3 ggrid(2, 1024);   // (n-blocks, m-blocks)
    xu_gemm<<<ggrid, 256, 0, stream>>>(x, wsB, bias, outDec);

    rnn_rec<<<256, 512, 0, stream>>>(enc, V, out);
}

// Round 2
// 547.744 us; speedup vs baseline: 1.1018x; 1.0444x over previous
//
#include <hip/hip_runtime.h>
#include <hip/hip_bf16.h>

// DecoderBlock: h_t = tanh(x_t @ U + h_{t-1} @ V + b)
// BZ=256, SEQ=512, IN=HID=256. fp32 in/out.
//
// prep_B : U (fp32) -> bf16 B-fragment-ordered buffer (128 KB).
// xu_gemm: XU = x @ U + b via bf16 MFMA 16x16x32 (unchanged).
// rnn_rec: h@V via fp16 MFMA (h broadcast into all 16 A-rows, identical C
//          rows -> no cross-wave reduce). THIS ROUND: raw s_barrier with
//          lgkmcnt(0) only -- __syncthreads() was draining vmcnt(0) every
//          step, serializing the per-step global XU load + h store latency
//          (~1000 cyc/step). Also: 2-deep MFMA chains (8 accumulators).

#define SEQn 512
#define HIDn 256

typedef __attribute__((ext_vector_type(4))) float    floatx4;
typedef __attribute__((ext_vector_type(8))) short    short8;
typedef __attribute__((ext_vector_type(8))) _Float16 half8;

// LDS-only barrier: drain LDS ops, then sync. Global loads/stores remain
// in flight across the barrier (their consumers get compiler vmcnt waits).
#define LDS_BARRIER() asm volatile("s_waitcnt lgkmcnt(0)\n\ts_barrier" ::: "memory")

__device__ __forceinline__ short f2bf(float f) {
    __hip_bfloat16 h = __float2bfloat16(f);
    return *reinterpret_cast<short*>(&h);
}

// ---------------------------------------------------------------------------
// Pack U[k][n] -> wsB chunks: chunk idx = (kb*4 + q)*256 + n holds
// U[kb*32 + q*8 + j][n] (j=0..7) as bf16. 8192 chunks x 16 B = 128 KB.
// ---------------------------------------------------------------------------
__global__ void prep_B(const float* __restrict__ U, short* __restrict__ wsB) {
    int idx = blockIdx.x * 256 + threadIdx.x;   // 0..8191
    int n  = idx & 255;
    int q  = (idx >> 8) & 3;
    int kb = idx >> 10;
    int k0 = kb * 32 + q * 8;
    short8 c;
    #pragma unroll
    for (int j = 0; j < 8; j++)
        c[j] = f2bf(U[(size_t)(k0 + j) * 256 + n]);
    *(short8*)(wsB + (size_t)idx * 8) = c;
}

// ---------------------------------------------------------------------------
// MFMA GEMM: block tile 128 rows x 128 cols, 4 waves. (unchanged)
// ---------------------------------------------------------------------------
__global__ __launch_bounds__(256, 4)
void xu_gemm(const float* __restrict__ X, const short* __restrict__ wsB,
             const float* __restrict__ bias, float* __restrict__ out)
{
    const int tid = threadIdx.x;
    const int l   = tid & 63;
    const int w   = tid >> 6;          // wave 0..3
    const int lr  = l & 15;
    const int q   = l >> 4;
    const int m0  = blockIdx.y * 128;
    const int n0  = blockIdx.x * 128;

    floatx4 acc[2][8];
    #pragma unroll
    for (int mt = 0; mt < 2; mt++)
        #pragma unroll
        for (int nt = 0; nt < 8; nt++)
            acc[mt][nt] = (floatx4){0.f, 0.f, 0.f, 0.f};

    const size_t rowA = (size_t)(m0 + 32 * w + lr);

    for (int kb = 0; kb < 8; kb++) {
        short8 af[2];
        #pragma unroll
        for (int mt = 0; mt < 2; mt++) {
            const float* p = X + (rowA + 16 * mt) * 256 + kb * 32 + q * 8;
            float4 a0 = *(const float4*)p;
            float4 a1 = *(const float4*)(p + 4);
            af[mt][0] = f2bf(a0.x); af[mt][1] = f2bf(a0.y);
            af[mt][2] = f2bf(a0.z); af[mt][3] = f2bf(a0.w);
            af[mt][4] = f2bf(a1.x); af[mt][5] = f2bf(a1.y);
            af[mt][6] = f2bf(a1.z); af[mt][7] = f2bf(a1.w);
        }
        #pragma unroll
        for (int nt = 0; nt < 8; nt++) {
            short8 bfr = *(const short8*)(wsB +
                ((size_t)(kb * 4 + q) * 256 + n0 + 16 * nt + lr) * 8);
            acc[0][nt] = __builtin_amdgcn_mfma_f32_16x16x32_bf16(af[0], bfr, acc[0][nt], 0, 0, 0);
            acc[1][nt] = __builtin_amdgcn_mfma_f32_16x16x32_bf16(af[1], bfr, acc[1][nt], 0, 0, 0);
        }
    }

    #pragma unroll
    for (int nt = 0; nt < 8; nt++) {
        float bv = bias[n0 + 16 * nt + lr];
        #pragma unroll
        for (int mt = 0; mt < 2; mt++) {
            #pragma unroll
            for (int r = 0; r < 4; r++) {
                int row = m0 + 32 * w + 16 * mt + 4 * q + r;
                out[(size_t)row * 256 + n0 + 16 * nt + lr] = acc[mt][nt][r] + bv;
            }
        }
    }
}

// ---------------------------------------------------------------------------
// Recurrence via MFMA. 1 WG per batch row, 512 threads (8 waves).
// Wave w owns output cols [32w, 32w+32) as 2 n-tiles of 16.
// A-frag: h broadcast to all 16 m-rows (address depends on quad only).
// B-frag: vf[nt][c][j] = fp16 V[32c+8q+j][32w+16nt+lr], preloaded (64 VGPR).
// C rows all identical -> acc[...][0] is the column sum in every lane.
// Single LDS-only barrier per step; XU prefetched 2 steps ahead and h
// stores never drained inside the loop.
// ---------------------------------------------------------------------------
__global__ __launch_bounds__(512, 2)
void rnn_rec(const float* __restrict__ enc, const float* __restrict__ V,
             float* __restrict__ out)
{
    __shared__ _Float16 hbuf[2][HIDn];   // ping-pong, 1 KB

    const int tid = threadIdx.x;
    const int w   = tid >> 6;        // wave 0..7
    const int l   = tid & 63;
    const int lr  = l & 15;
    const int q   = l >> 4;
    const int b   = blockIdx.x;
    const int c0  = 32 * w + lr;     // first owned column (nt=0)

    // ---- preload V as fp16 B-fragments: 16 frags x 8 halves = 64 VGPR ----
    half8 vf[2][8];
    #pragma unroll
    for (int c = 0; c < 8; c++) {
        const float* vp = V + (size_t)(32 * c + 8 * q) * HIDn + 32 * w + lr;
        #pragma unroll
        for (int nt = 0; nt < 2; nt++) {
            half8 tmp;
            #pragma unroll
            for (int j = 0; j < 8; j++)
                tmp[j] = (_Float16)vp[(size_t)j * HIDn + 16 * nt];
            vf[nt][c] = tmp;
        }
    }

    float* outEnc = out + (size_t)b * HIDn;
    float* outDec = out + (size_t)65536 + (size_t)b * SEQn * HIDn;

    // ---- h0 init + encoder passthrough ----
    if (tid < HIDn) {
        float h0 = enc[(size_t)b * HIDn + tid];
        outEnc[tid]  = h0;
        hbuf[0][tid] = (_Float16)h0;
    }

    // ---- XU prefetch pipeline, depth 2 (rows t and t+1 preloaded) ----
    float xu_cur0 = outDec[c0];
    float xu_cur1 = outDec[c0 + 16];
    float xu_nx0  = outDec[HIDn + c0];
    float xu_nx1  = outDec[HIDn + c0 + 16];

    LDS_BARRIER();

    int p = 0;
    for (int t = 0; t < SEQn; t++) {
        // prefetch XU for t+2 (stays in flight across the whole step now)
        float pf0 = 0.f, pf1 = 0.f;
        if (t + 2 < SEQn) {
            const float* xp = outDec + (size_t)(t + 2) * HIDn;
            pf0 = xp[c0];
            pf1 = xp[c0 + 16];
        }

        // A-fragments: 8 k-chunks, 16 B each, address depends on quad only
        // (broadcast read -> identical A rows)
        half8 af[8];
        #pragma unroll
        for (int c = 0; c < 8; c++)
            af[c] = *(const half8*)&hbuf[p][32 * c + 8 * q];

        // 16 MFMAs as 8 independent 2-deep chains
        floatx4 acc[2][4];
        #pragma unroll
        for (int nt = 0; nt < 2; nt++)
            #pragma unroll
            for (int ch = 0; ch < 4; ch++)
                acc[nt][ch] = (floatx4){0.f,0.f,0.f,0.f};
        #pragma unroll
        for (int c = 0; c < 8; c++) {
            acc[0][c & 3] = __builtin_amdgcn_mfma_f32_16x16x32_f16(af[c], vf[0][c], acc[0][c & 3], 0, 0, 0);
            acc[1][c & 3] = __builtin_amdgcn_mfma_f32_16x16x32_f16(af[c], vf[1][c], acc[1][c & 3], 0, 0, 0);
        }

        float s0 = ((acc[0][0][0] + acc[0][1][0]) + (acc[0][2][0] + acc[0][3][0])) + xu_cur0;
        float s1 = ((acc[1][0][0] + acc[1][1][0]) + (acc[1][2][0] + acc[1][3][0])) + xu_cur1;
        float e0 = __expf(2.f * s0);
        float e1 = __expf(2.f * s1);
        float hv0 = 1.f - 2.f / (e0 + 1.f);
        float hv1 = 1.f - 2.f / (e1 + 1.f);

        if (q == 0) {   // quads 1-3 hold duplicates; one writer per column
            hbuf[p ^ 1][c0]      = (_Float16)hv0;
            hbuf[p ^ 1][c0 + 16] = (_Float16)hv1;
            float* op = outDec + (size_t)t * HIDn;
            op[c0]      = hv0;
            op[c0 + 16] = hv1;
        }

        xu_cur0 = xu_nx0; xu_cur1 = xu_nx1;
        xu_nx0  = pf0;    xu_nx1  = pf1;
        p ^= 1;
        LDS_BARRIER();   // LDS-only drain: global ops stay in flight
    }
}

extern "C" void kernel_launch(void* const* d_in, const int* in_sizes, int n_in,
                              void* d_out, int out_size, void* d_ws, size_t ws_size,
                              hipStream_t stream) {
    const float* enc  = (const float*)d_in[0];   // [256,256]
    const float* x    = (const float*)d_in[1];   // [256,512,256]
    const float* U    = (const float*)d_in[2];   // [256,256]
    const float* V    = (const float*)d_in[3];   // [256,256]
    const float* bias = (const float*)d_in[4];   // [256]
    float* out = (float*)d_out;                  // 65536 + 33554432 floats

    float* outDec = out + 65536;

    // bf16 B-frag scratch (128 KB): d_ws, or the 256 KB encoder-output region
    // of d_out as fallback (rnn_rec overwrites it only after xu_gemm is done).
    short* wsB = (ws_size >= 131072) ? (short*)d_ws : (short*)out;

    prep_B<<<32, 256, 0, stream>>>(U, wsB);

    dim3 ggrid(2, 1024);   // (n-blocks, m-blocks)
    xu_gemm<<<ggrid, 256, 0, stream>>>(x, wsB, bias, outDec);

    rnn_rec<<<256, 512, 0, stream>>>(enc, V, out);
}